// Round 16
// baseline (296.482 us; speedup 1.0000x reference)
//
#include <hip/hip_runtime.h>
#include <hip/hip_cooperative_groups.h>

namespace cg = cooperative_groups;

#define IN_F 4096
#define OUT_F 4096
#define KGRP 16
#define N_ROWS (8 * 2048)
#define WPARTS 32                  // wsum partial chunks

// Cooperative config: 512 blocks = 2/CU, launch_bounds(256,2) -> VGPR<=256,
// large co-residency margin (R14 failed at 1024 blocks/(256,4): exact-fit
// occupancy -> cooperative launch rejected -> zeros).
#define CBLK 512
#define RPB_C (N_ROWS / CBLK)      // 32 rows per block (cooperative)
#define RPB_F 8                    // rows per block (fallback kernels)
#define NBLK_F (N_ROWS / RPB_F)    // 2048 fallback blocks
#define PLAIN_ROWS 8192            // x rows read with plain loads (R15 policy)

typedef float f32x4 __attribute__((ext_vector_type(4)));

// d_ws layout (16B-aligned):
//   [0,      32KB)   : wsum    double[4096]
//   [32KB,   96KB)   : S       float[16384]    (fallback path only)
//   [96KB,  1120KB)  : partial double[32][4096]

// ===========================================================================
// COOPERATIVE MEGA-KERNEL: wsum partials -> reduce -> srow -> out with
// grid.sync() between phases (replaces ~15us of dispatch gaps).
// Phase purity preserved. S kept in LDS across syncs (blocks persistent).
// Cache policy = R15: x rows<8192 plain, rest NT; w NT; out NT stores.
// ===========================================================================
__global__ __launch_bounds__(256, 2) void mega_kernel(const float* __restrict__ x,
                                                      const float* __restrict__ w,
                                                      const float* __restrict__ bias,
                                                      float* __restrict__ out,
                                                      double* __restrict__ partial,
                                                      double* __restrict__ wsum) {
    cg::grid_group grid = cg::this_grid();
    const int t = threadIdx.x;
    const int b = blockIdx.x;
    const int lane = t & 63;
    const int wave = t >> 6;

    // ---- Phase 1: wsum partials (R13 A/B winner: strided, 512 blocks) ----
    {
        const int bx = b & 15;          // column group [0,16)
        const int by = b >> 4;          // row chunk   [0,32)
        const int f = bx * 256 + t;
        const float* p = w + (size_t)(by * (OUT_F / WPARTS)) * IN_F + f;
        double s = 0.0;
#pragma unroll 16
        for (int o = 0; o < OUT_F / WPARTS; ++o)
            s += (double)__builtin_nontemporal_load(&p[(size_t)o * IN_F]);
        partial[by * IN_F + f] = s;
    }
    grid.sync();

    // ---- Phase 1b: reduce, parallel over ALL blocks.
    // 512 blocks x 256 threads = 131072 = 4096 cols x 32 parts exactly.
    // Thread handles (col = b*8 + t>>5, p = t&31); width-32 shfl tree. ----
    {
        const int col = b * 8 + (t >> 5);
        const int p = t & 31;
        double v = partial[(size_t)p * IN_F + col];
#pragma unroll
        for (int off = 16; off > 0; off >>= 1)
            v += __shfl_xor(v, off, 32);
        if (p == 0) wsum[col] = v;
    }
    grid.sync();

    // ---- Phase 2: srow (pure read). S -> LDS only. ----
    __shared__ double g[RPB_C][KGRP];
    __shared__ float sS[RPB_C];

    double wreg[16];
#pragma unroll
    for (int k = 0; k < 4; ++k) {
        const double* wp = &wsum[4 * (k * 256 + t)];
        double2 w01 = *(const double2*)(wp);
        double2 w23 = *(const double2*)(wp + 2);
        wreg[4 * k + 0] = w01.x; wreg[4 * k + 1] = w01.y;
        wreg[4 * k + 2] = w23.x; wreg[4 * k + 3] = w23.y;
    }
    const f32x4* b4 = (const f32x4*)bias;
    f32x4 bb[4];
#pragma unroll
    for (int k = 0; k < 4; ++k) bb[k] = b4[k * 256 + t];

    const int n0 = b * RPB_C;
    const bool pinned = (b < CBLK / 2);   // rows < 8192: plain loads

    for (int r = 0; r < RPB_C; ++r) {
        const f32x4* xr = (const f32x4*)(x + (size_t)(n0 + r) * IN_F);
        double part[4];
        if (pinned) {
#pragma unroll
            for (int k = 0; k < 4; ++k) {
                f32x4 v = xr[k * 256 + t];
                part[k] = (double)v.x * wreg[4 * k + 0] + (double)v.y * wreg[4 * k + 1] +
                          (double)v.z * wreg[4 * k + 2] + (double)v.w * wreg[4 * k + 3];
            }
        } else {
#pragma unroll
            for (int k = 0; k < 4; ++k) {
                f32x4 v = __builtin_nontemporal_load(&xr[k * 256 + t]);
                part[k] = (double)v.x * wreg[4 * k + 0] + (double)v.y * wreg[4 * k + 1] +
                          (double)v.z * wreg[4 * k + 2] + (double)v.w * wreg[4 * k + 3];
            }
        }
        // folded butterfly: 4 values over 64 lanes in 7 shfls
        double keep01 = (lane & 1) ? part[1] : part[0];
        double send01 = (lane & 1) ? part[0] : part[1];
        double keep23 = (lane & 1) ? part[3] : part[2];
        double send23 = (lane & 1) ? part[2] : part[3];
        double w01 = keep01 + __shfl_xor(send01, 1, 64);
        double w23 = keep23 + __shfl_xor(send23, 1, 64);
        double keep = (lane & 2) ? w23 : w01;
        double send = (lane & 2) ? w01 : w23;
        double rv = keep + __shfl_xor(send, 2, 64);
#pragma unroll
        for (int off = 4; off <= 32; off <<= 1)
            rv += __shfl_xor(rv, off, 64);
        if (lane < 4) g[r][lane * 4 + wave] = rv;
    }
    __syncthreads();

    if (t < RPB_C) {
        double cs = 0.0, Sv = 0.0;
        bool found = false;
#pragma unroll
        for (int k = 0; k < KGRP; ++k) {
            cs += g[t][k];
            if (!found && cs >= 0.0) { Sv = cs; found = true; }
        }
        if (!found) Sv = cs;
        sS[t] = (float)Sv;
    }
    __syncthreads();

    grid.sync();   // phase purity: all x reads complete before out writes

    // ---- Phase 3: out (pure write, NT stores) ----
    for (int r = 0; r < RPB_C; ++r) {
        const float Sv = sS[r];
        f32x4* o4 = (f32x4*)(out + (size_t)(n0 + r) * OUT_F);
#pragma unroll
        for (int k = 0; k < 4; ++k) {
            f32x4 rr;
            rr.x = __builtin_amdgcn_rcpf(1.0f + __expf(-(Sv + bb[k].x)));
            rr.y = __builtin_amdgcn_rcpf(1.0f + __expf(-(Sv + bb[k].y)));
            rr.z = __builtin_amdgcn_rcpf(1.0f + __expf(-(Sv + bb[k].z)));
            rr.w = __builtin_amdgcn_rcpf(1.0f + __expf(-(Sv + bb[k].w)));
            __builtin_nontemporal_store(rr, &o4[k * 256 + t]);
        }
    }
}

// ===========================================================================
// FALLBACK PATH (R15-exact, 118.7us known-good) — used if cooperative
// launch is rejected.
// ===========================================================================
__global__ __launch_bounds__(256) void wsum_partial_kernel(const float* __restrict__ w,
                                                           double* __restrict__ partial) {
    const int f = blockIdx.x * 256 + threadIdx.x;
    const int r0 = blockIdx.y * (OUT_F / WPARTS);
    const float* p = w + (size_t)r0 * IN_F + f;
    double s = 0.0;
#pragma unroll 16
    for (int o = 0; o < OUT_F / WPARTS; ++o)
        s += (double)__builtin_nontemporal_load(&p[(size_t)o * IN_F]);
    partial[blockIdx.y * IN_F + f] = s;
}

__global__ __launch_bounds__(256) void wsum_reduce_kernel(const double* __restrict__ partial,
                                                          double* __restrict__ wsum) {
    const int f = blockIdx.x * 256 + threadIdx.x;
    double s = 0.0;
#pragma unroll
    for (int p = 0; p < WPARTS; ++p) s += partial[p * IN_F + f];
    wsum[f] = s;
}

__global__ __launch_bounds__(256) void srow_kernel(const float* __restrict__ x,
                                                   const double* __restrict__ wsum,
                                                   float* __restrict__ S) {
    const int t = threadIdx.x;
    const int lane = t & 63;
    const int wave = t >> 6;
    const int n0 = blockIdx.x * RPB_F;
    const bool pinned = (n0 < PLAIN_ROWS);

    __shared__ double g[RPB_F][KGRP];

    double wreg[16];
#pragma unroll
    for (int k = 0; k < 4; ++k) {
        const double* wp = &wsum[4 * (k * 256 + t)];
        double2 w01 = *(const double2*)(wp);
        double2 w23 = *(const double2*)(wp + 2);
        wreg[4 * k + 0] = w01.x; wreg[4 * k + 1] = w01.y;
        wreg[4 * k + 2] = w23.x; wreg[4 * k + 3] = w23.y;
    }

    for (int r = 0; r < RPB_F; ++r) {
        const f32x4* xr = (const f32x4*)(x + (size_t)(n0 + r) * IN_F);
        double part[4];
        if (pinned) {
#pragma unroll
            for (int k = 0; k < 4; ++k) {
                f32x4 v = xr[k * 256 + t];
                part[k] = (double)v.x * wreg[4 * k + 0] + (double)v.y * wreg[4 * k + 1] +
                          (double)v.z * wreg[4 * k + 2] + (double)v.w * wreg[4 * k + 3];
            }
        } else {
#pragma unroll
            for (int k = 0; k < 4; ++k) {
                f32x4 v = __builtin_nontemporal_load(&xr[k * 256 + t]);
                part[k] = (double)v.x * wreg[4 * k + 0] + (double)v.y * wreg[4 * k + 1] +
                          (double)v.z * wreg[4 * k + 2] + (double)v.w * wreg[4 * k + 3];
            }
        }
        double keep01 = (lane & 1) ? part[1] : part[0];
        double send01 = (lane & 1) ? part[0] : part[1];
        double keep23 = (lane & 1) ? part[3] : part[2];
        double send23 = (lane & 1) ? part[2] : part[3];
        double w01 = keep01 + __shfl_xor(send01, 1, 64);
        double w23 = keep23 + __shfl_xor(send23, 1, 64);
        double keep = (lane & 2) ? w23 : w01;
        double send = (lane & 2) ? w01 : w23;
        double rv = keep + __shfl_xor(send, 2, 64);
#pragma unroll
        for (int off = 4; off <= 32; off <<= 1)
            rv += __shfl_xor(rv, off, 64);
        if (lane < 4) g[r][lane * 4 + wave] = rv;
    }
    __syncthreads();

    if (t < RPB_F) {
        double cs = 0.0, Sv = 0.0;
        bool found = false;
#pragma unroll
        for (int k = 0; k < KGRP; ++k) {
            cs += g[t][k];
            if (!found && cs >= 0.0) { Sv = cs; found = true; }
        }
        if (!found) Sv = cs;
        S[n0 + t] = (float)Sv;
    }
}

__global__ __launch_bounds__(256) void out_kernel(const float* __restrict__ S,
                                                  const float* __restrict__ bias,
                                                  float* __restrict__ out) {
    const int t = threadIdx.x;
    const int n0 = blockIdx.x * RPB_F;
    const f32x4* b4 = (const f32x4*)bias;

    f32x4 b[4];
#pragma unroll
    for (int k = 0; k < 4; ++k) b[k] = b4[k * 256 + t];

    for (int r = 0; r < RPB_F; ++r) {
        const float Sv = S[n0 + r];
        f32x4* o4 = (f32x4*)(out + (size_t)(n0 + r) * OUT_F);
#pragma unroll
        for (int k = 0; k < 4; ++k) {
            f32x4 rr;
            rr.x = __builtin_amdgcn_rcpf(1.0f + __expf(-(Sv + b[k].x)));
            rr.y = __builtin_amdgcn_rcpf(1.0f + __expf(-(Sv + b[k].y)));
            rr.z = __builtin_amdgcn_rcpf(1.0f + __expf(-(Sv + b[k].z)));
            rr.w = __builtin_amdgcn_rcpf(1.0f + __expf(-(Sv + b[k].w)));
            __builtin_nontemporal_store(rr, &o4[k * 256 + t]);
        }
    }
}

extern "C" void kernel_launch(void* const* d_in, const int* in_sizes, int n_in,
                              void* d_out, int out_size, void* d_ws, size_t ws_size,
                              hipStream_t stream) {
    const float* x    = (const float*)d_in[0];   // [8,2048,4096] f32
    const float* w    = (const float*)d_in[1];   // [4096,4096]   f32
    const float* bias = (const float*)d_in[2];   // [4096]        f32
    float* out = (float*)d_out;                  // [8,2048,4096] f32

    char* ws = (char*)d_ws;
    double* wsum    = (double*)(ws);                 // 4096 f64
    float*  S       = (float*)(ws + 32 * 1024);      // 16384 f32 (fallback)
    double* partial = (double*)(ws + 96 * 1024);     // 32*4096 f64

    void* args[] = {(void*)&x, (void*)&w, (void*)&bias, (void*)&out,
                    (void*)&partial, (void*)&wsum};
    hipError_t err = hipLaunchCooperativeKernel((void*)mega_kernel, dim3(CBLK),
                                                dim3(256), args, 0, stream);
    if (err != hipSuccess) {
        // Fallback: proven 4-dispatch path (R15, 118.7us)
        dim3 g1(IN_F / 256, WPARTS);
        wsum_partial_kernel<<<g1, 256, 0, stream>>>(w, partial);
        wsum_reduce_kernel<<<IN_F / 256, 256, 0, stream>>>(partial, wsum);
        srow_kernel<<<NBLK_F, 256, 0, stream>>>(x, wsum, S);
        out_kernel<<<NBLK_F, 256, 0, stream>>>(S, bias, out);
    }
}